// Round 1
// baseline (126.294 us; speedup 1.0000x reference)
//
#include <hip/hip_runtime.h>
#include <hip/hip_bf16.h>

#define N 8192
#define D 256
// sim = dot / 0.5 = 2*dot; fixed softmax shift = 2.0 (max possible sim, self-sim)

typedef __attribute__((ext_vector_type(8))) short bf16x8;   // 8 bf16 = 4 VGPRs
typedef __attribute__((ext_vector_type(4))) float f32x4;    // MFMA 16x16 accumulator

#define BM 128            // rows per block (4 waves x 32)
#define BN 64             // cols per LDS tile
#define COLS_PER_BLK 512  // col range per block
#define NT (COLS_PER_BLK / BN)   // 8 col-tile iterations
#define ROWBLKS (N / BM)         // 64
#define COLBLKS (N / COLS_PER_BLK) // 16

__device__ inline unsigned short f2bf(float x) {
    __hip_bfloat16 h = __float2bfloat16(x);
    return *reinterpret_cast<unsigned short*>(&h);
}

// ---------------- kernel 1: fp32 -> bf16 convert + zero accumulators ----------------
__global__ void convert_kernel(const float4* __restrict__ E4, ushort4* __restrict__ Ebf4,
                               float* __restrict__ Z, float* __restrict__ P, float* __restrict__ C) {
    int i = blockIdx.x * blockDim.x + threadIdx.x;
    int n4 = (N * D) / 4;
    if (i < n4) {
        float4 v = E4[i];
        ushort4 o;
        o.x = f2bf(v.x); o.y = f2bf(v.y); o.z = f2bf(v.z); o.w = f2bf(v.w);
        Ebf4[i] = o;
    }
    if (i < N) { Z[i] = 0.0f; P[i] = 0.0f; C[i] = 0.0f; }
}

// ---------------- kernel 2: fused sim + masked online-softmax accumulation ----------------
// grid = ROWBLKS*COLBLKS blocks of 256 threads.
// Each block: rows [r0, r0+128) x cols [c0, c0+512).
// Wave w owns rows r0 + w*32 .. +32 (2 row-groups of 16); A-frags live in registers.
// B tile (64 cols x 256 K, bf16, 32 KB) staged in LDS via global_load_lds(16B),
// XOR-swizzled (inner ^= (row&7)<<4) via pre-swizzled global source (linear LDS dest).
__global__ __launch_bounds__(256)
void sim_kernel(const __hip_bfloat16* __restrict__ Ebf,
                const int* __restrict__ labels,
                float* __restrict__ Z, float* __restrict__ P, float* __restrict__ C) {
    __shared__ unsigned char Bsh[BN * 512];   // 64 rows x 512 B (bf16 K=256), swizzled
    __shared__ int Lcol[COLS_PER_BLK];

    const int tid  = threadIdx.x;
    const int lane = tid & 63;
    const int wid  = tid >> 6;
    const int blk  = blockIdx.x;
    const int r0   = (blk >> 4) * BM;            // row block
    const int c0   = (blk & 15) * COLS_PER_BLK;  // col split

    // stage this block's column labels
    for (int t = tid; t < COLS_PER_BLK; t += 256) Lcol[t] = labels[c0 + t];

    const char* ebase = (const char*)Ebf;

    // A fragments: layout for mfma_f32_16x16x32_bf16 A-operand:
    // row = lane&15, k = (lane>>4)*8 + j  -> 16 contiguous bytes per lane per k-group
    bf16x8 a[2][8];
#pragma unroll
    for (int rg = 0; rg < 2; ++rg) {
        int row = r0 + wid * 32 + rg * 16 + (lane & 15);
        const char* rp = ebase + (size_t)row * (D * 2) + ((lane >> 4) * 16);
#pragma unroll
        for (int kg = 0; kg < 8; ++kg)
            a[rg][kg] = *reinterpret_cast<const bf16x8*>(rp + kg * 64);
    }

    // labels of this lane's output rows (C/D layout: row = (lane>>4)*4 + r)
    int labi[2][4];
#pragma unroll
    for (int rg = 0; rg < 2; ++rg)
#pragma unroll
        for (int r = 0; r < 4; ++r)
            labi[rg][r] = labels[r0 + wid * 32 + rg * 16 + (lane >> 4) * 4 + r];

    float zacc[2][4] = {{0}}, pacc[2][4] = {{0}}, cacc[2][4] = {{0}};

    for (int ct = 0; ct < NT; ++ct) {
        __syncthreads();  // previous tile's reads done before overwrite
#pragma unroll
        for (int m = 0; m < 8; ++m) {
            unsigned obase = m * 4096 + wid * 1024;          // wave-uniform LDS dest
            unsigned o     = obase + lane * 16;              // this lane's linear slot
            unsigned row   = o >> 9;                         // tile row (0..63)
            unsigned inner = (o & 511) ^ ((row & 7) << 4);   // inverse swizzle on source
            const char* src = ebase + (size_t)(c0 + ct * 64 + row) * (D * 2) + inner;
            __builtin_amdgcn_global_load_lds(
                (const __attribute__((address_space(1))) void*)src,
                (__attribute__((address_space(3))) void*)(Bsh + obase), 16, 0, 0);
        }
        __syncthreads();  // drains vmcnt before barrier (compiler-enforced)

        f32x4 acc[2][4];
#pragma unroll
        for (int rg = 0; rg < 2; ++rg)
#pragma unroll
            for (int cg = 0; cg < 4; ++cg) acc[rg][cg] = (f32x4){0.f, 0.f, 0.f, 0.f};

#pragma unroll
        for (int cg = 0; cg < 4; ++cg) {
            int col = cg * 16 + (lane & 15);
            unsigned rowbase = (unsigned)col * 512;
            unsigned ib = (lane >> 4) * 16;
#pragma unroll
            for (int kg = 0; kg < 8; ++kg) {
                unsigned inner = (ib + kg * 64) ^ ((col & 7) << 4);  // swizzled read
                bf16x8 b = *reinterpret_cast<const bf16x8*>(Bsh + rowbase + inner);
                acc[0][cg] = __builtin_amdgcn_mfma_f32_16x16x32_bf16(a[0][kg], b, acc[0][cg], 0, 0, 0);
                acc[1][cg] = __builtin_amdgcn_mfma_f32_16x16x32_bf16(a[1][kg], b, acc[1][cg], 0, 0, 0);
            }
        }

        // fused epilogue: exp + masked accumulation (C/D: col=lane&15, row=(lane>>4)*4+r)
#pragma unroll
        for (int rg = 0; rg < 2; ++rg)
#pragma unroll
            for (int cg = 0; cg < 4; ++cg) {
                int jloc = ct * 64 + cg * 16 + (lane & 15);
                int j    = c0 + jloc;
                int labj = Lcol[jloc];
#pragma unroll
                for (int r = 0; r < 4; ++r) {
                    int i = r0 + wid * 32 + rg * 16 + (lane >> 4) * 4 + r;
                    float s = 2.0f * acc[rg][cg][r];
                    float e = __expf(s - 2.0f);
                    bool diag = (i == j);
                    bool pos  = (labi[rg][r] == labj) && !diag;
                    zacc[rg][r] += diag ? 0.0f : e;
                    pacc[rg][r] += pos ? s : 0.0f;
                    cacc[rg][r] += pos ? 1.0f : 0.0f;
                }
            }
    }

    // reduce over the 16 lanes sharing (lane>>4); then one atomic per row
#pragma unroll
    for (int rg = 0; rg < 2; ++rg)
#pragma unroll
        for (int r = 0; r < 4; ++r) {
            float z = zacc[rg][r], p = pacc[rg][r], c = cacc[rg][r];
#pragma unroll
            for (int m = 8; m >= 1; m >>= 1) {
                z += __shfl_xor(z, m, 64);
                p += __shfl_xor(p, m, 64);
                c += __shfl_xor(c, m, 64);
            }
            if ((lane & 15) == 0) {
                int i = r0 + wid * 32 + rg * 16 + (lane >> 4) * 4 + r;
                atomicAdd(&Z[i], z);
                atomicAdd(&P[i], p);
                atomicAdd(&C[i], c);
            }
        }
}

// ---------------- kernel 3: per-row finalize + scalar reduce ----------------
__global__ void finalize_kernel(const float* __restrict__ Z, const float* __restrict__ P,
                                const float* __restrict__ C, float* __restrict__ out) {
    __shared__ float snum[256], sden[256];
    float num = 0.0f, den = 0.0f;
    for (int i = threadIdx.x; i < N; i += 256) {
        float c = C[i];
        // per-row contribution: c_i*(log Z_i + shift) - P_i   (shift = 2)
        num += c * (2.0f + logf(Z[i])) - P[i];
        den += c;
    }
    snum[threadIdx.x] = num; sden[threadIdx.x] = den;
    __syncthreads();
    for (int s = 128; s > 0; s >>= 1) {
        if (threadIdx.x < s) {
            snum[threadIdx.x] += snum[threadIdx.x + s];
            sden[threadIdx.x] += sden[threadIdx.x + s];
        }
        __syncthreads();
    }
    if (threadIdx.x == 0) out[0] = snum[0] / sden[0];
}

extern "C" void kernel_launch(void* const* d_in, const int* in_sizes, int n_in,
                              void* d_out, int out_size, void* d_ws, size_t ws_size,
                              hipStream_t stream) {
    const float* emb   = (const float*)d_in[0];
    const int* labels  = (const int*)d_in[1];
    float* out = (float*)d_out;

    char* ws = (char*)d_ws;
    __hip_bfloat16* Ebf = (__hip_bfloat16*)ws;           // 8192*256*2 = 4 MB
    float* Z = (float*)(ws + (size_t)N * D * 2);         // 32 KB
    float* P = Z + N;
    float* C = P + N;

    convert_kernel<<<(N * D / 4 + 255) / 256, 256, 0, stream>>>(
        (const float4*)emb, (ushort4*)Ebf, Z, P, C);
    sim_kernel<<<ROWBLKS * COLBLKS, 256, 0, stream>>>(Ebf, labels, Z, P, C);
    finalize_kernel<<<1, 256, 0, stream>>>(Z, P, C, out);
}

// Round 2
// 113.233 us; speedup vs baseline: 1.1153x; 1.1153x over previous
//
#include <hip/hip_runtime.h>
#include <hip/hip_bf16.h>

#define N 8192
#define D 256
// sim = dot/0.5 = 2*dot; normalized rows -> s_ii ~= 2. Fixed shift of 2.0 replaces row-max
// (log-sum-exp is shift-invariant). Diagonal and positive-count handled analytically.

typedef __attribute__((ext_vector_type(8))) short bf16x8;   // 8 bf16 = 4 VGPRs
typedef __attribute__((ext_vector_type(4))) float f32x4;    // MFMA 16x16 accumulator

#define BM 128            // rows per block (4 waves x 32)
#define BN 64             // cols per LDS tile
#define COLS_PER_BLK 512
#define NT (COLS_PER_BLK / BN)      // 8
#define ROWBLKS (N / BM)            // 64
#define COLBLKS (N / COLS_PER_BLK)  // 16

#define K1 2.8853900817779268f   // 2*log2(e)
#define K2 (-2.8853900817779268f)

__device__ inline unsigned short f2bf(float x) {
    __hip_bfloat16 h = __float2bfloat16(x);
    return *reinterpret_cast<unsigned short*>(&h);
}

__device__ inline float fast_exp2(float t) {
#if __has_builtin(__builtin_amdgcn_exp2f)
    return __builtin_amdgcn_exp2f(t);
#else
    return __expf(t * 0.69314718056f);
#endif
}

// ---------------- kernel 1: fp32 -> bf16 convert + zero accumulators ----------------
__global__ void convert_kernel(const float4* __restrict__ E4, ushort4* __restrict__ Ebf4,
                               float* __restrict__ Z, float* __restrict__ P,
                               float* __restrict__ nd) {
    int i = blockIdx.x * blockDim.x + threadIdx.x;
    int n4 = (N * D) / 4;
    if (i < n4) {
        float4 v = E4[i];
        ushort4 o;
        o.x = f2bf(v.x); o.y = f2bf(v.y); o.z = f2bf(v.z); o.w = f2bf(v.w);
        Ebf4[i] = o;
    }
    if (i < N) { Z[i] = 0.0f; P[i] = 0.0f; }
    if (i < 2) nd[i] = 0.0f;
}

// ---------------- kernel 2: fused sim + exp-sum + masked dot-sum ----------------
// grid = 1024 blocks x 256 thr. Block: rows [r0,r0+128) x cols [c0,c0+512).
// LDS B layout: addr(col,k) = (k>>5)*4096 + ((col*64 + ((k>>3)&3)*16) ^ (((col>>1)&3)<<4)) + (k&7)*2
// -> K-loop ds_reads use one base reg + offset:kg*4096 immediates; conflict-free per 16-lane phase.
__global__ __launch_bounds__(256)
void sim_kernel(const __hip_bfloat16* __restrict__ Ebf,
                const int* __restrict__ labels,
                float* __restrict__ Z, float* __restrict__ P) {
    __shared__ unsigned char Bsh[BN * 512];   // 32 KB
    __shared__ int Lcol[COLS_PER_BLK];        // 2 KB

    const int tid  = threadIdx.x;
    const int lane = tid & 63;
    const int wid  = tid >> 6;
    const int blk  = blockIdx.x;
    const int r0   = (blk >> 4) * BM;
    const int c0   = (blk & 15) * COLS_PER_BLK;

    for (int t = tid; t < COLS_PER_BLK; t += 256) Lcol[t] = labels[c0 + t];

    const char* ebase = (const char*)Ebf;

    // A fragments (row = lane&15, k-seg = lane>>4): 2 row-groups x 8 kg x 16B
    bf16x8 a[2][8];
#pragma unroll
    for (int rg = 0; rg < 2; ++rg) {
        int row = r0 + wid * 32 + rg * 16 + (lane & 15);
        const char* rp = ebase + (size_t)row * (D * 2) + ((lane >> 4) * 16);
#pragma unroll
        for (int kg = 0; kg < 8; ++kg)
            a[rg][kg] = *reinterpret_cast<const bf16x8*>(rp + kg * 64);
    }

    // labels of this lane's output rows (C/D row = (lane>>4)*4 + r)
    int labi[2][4];
#pragma unroll
    for (int rg = 0; rg < 2; ++rg)
#pragma unroll
        for (int r = 0; r < 4; ++r)
            labi[rg][r] = labels[r0 + wid * 32 + rg * 16 + (lane >> 4) * 4 + r];

    // ct-invariant swizzled LDS read bases, one per cg
    unsigned rbase[4];
#pragma unroll
    for (int cg = 0; cg < 4; ++cg) {
        unsigned col = cg * 16 + (lane & 15);
        unsigned seg = lane >> 4;
        rbase[cg] = (col * 64 + seg * 16) ^ (((col >> 1) & 3) << 4);
    }

    float zacc[2][4] = {{0}}, pacc[2][4] = {{0}};

    for (int ct = 0; ct < NT; ++ct) {
        __syncthreads();
        // stage 64 cols x 256 k (32 KB): 8 chunks of 1KB per wave, linear dest,
        // inverse-swizzled source (swizzle permutes 16B segs within a col's 64B)
#pragma unroll
        for (int m = 0; m < 8; ++m) {
            int c = wid * 8 + m;                 // chunk 0..31
            int kg = c >> 2, colblk = c & 3;
            unsigned dbase = kg * 4096 + colblk * 1024;   // wave-uniform
            int colLocal = colblk * 16 + (lane >> 2);
            int seg_src  = (lane & 3) ^ ((colLocal >> 1) & 3);
            const char* src = ebase + (size_t)(c0 + ct * 64 + colLocal) * 512
                            + kg * 64 + seg_src * 16;
            __builtin_amdgcn_global_load_lds(
                (const __attribute__((address_space(1))) void*)src,
                (__attribute__((address_space(3))) void*)(Bsh + dbase), 16, 0, 0);
        }
        __syncthreads();

        f32x4 acc[2][4];
#pragma unroll
        for (int rg = 0; rg < 2; ++rg)
#pragma unroll
            for (int cg = 0; cg < 4; ++cg) acc[rg][cg] = (f32x4){0.f, 0.f, 0.f, 0.f};

#pragma unroll
        for (int cg = 0; cg < 4; ++cg) {
#pragma unroll
            for (int kg = 0; kg < 8; ++kg) {
                bf16x8 b = *reinterpret_cast<const bf16x8*>(Bsh + rbase[cg] + kg * 4096);
                acc[0][cg] = __builtin_amdgcn_mfma_f32_16x16x32_bf16(a[0][kg], b, acc[0][cg], 0, 0, 0);
                acc[1][cg] = __builtin_amdgcn_mfma_f32_16x16x32_bf16(a[1][kg], b, acc[1][cg], 0, 0, 0);
            }
        }

        // epilogue: Z += exp2(fma(acc)); P += (labi==labj) ? acc : 0   (raw dot; x2 later)
#pragma unroll
        for (int cg = 0; cg < 4; ++cg) {
            int labj = Lcol[ct * 64 + cg * 16 + (lane & 15)];
#pragma unroll
            for (int rg = 0; rg < 2; ++rg)
#pragma unroll
                for (int r = 0; r < 4; ++r) {
                    float d = acc[rg][cg][r];
                    zacc[rg][r] += fast_exp2(__builtin_fmaf(d, K1, K2));
                    pacc[rg][r] += (labi[rg][r] == labj) ? d : 0.0f;
                }
        }
    }

    // reduce over the 16 lanes (cols) sharing each output row, then 1 atomic/row
#pragma unroll
    for (int rg = 0; rg < 2; ++rg)
#pragma unroll
        for (int r = 0; r < 4; ++r) {
            float z = zacc[rg][r], p = pacc[rg][r];
#pragma unroll
            for (int m = 1; m <= 8; m <<= 1) {
                z += __shfl_xor(z, m, 64);
                p += __shfl_xor(p, m, 64);
            }
            if ((lane & 15) == 0) {
                int i = r0 + wid * 32 + rg * 16 + (lane >> 4) * 4 + r;
                atomicAdd(&Z[i], z);
                atomicAdd(&P[i], p);
            }
        }
}

// ---------------- kernel 3: per-row finalize (hist + num/den partials) ----------------
__global__ void finalize_kernel(const float* __restrict__ Z, const float* __restrict__ P,
                                const int* __restrict__ labels, float* __restrict__ nd) {
    __shared__ int hist[64];
    __shared__ float snum[256], sden[256];
    int t = threadIdx.x;
    if (t < 64) hist[t] = 0;
    __syncthreads();
    for (int i = t; i < N; i += 256) atomicAdd(&hist[labels[i]], 1);
    __syncthreads();

    int i = blockIdx.x * 256 + t;
    // diag removal: Z includes exp(s_ii-2)~=1 ; P includes dot_ii ~= 1 (x2 scale)
    float z = Z[i] - 1.0f;
    float p = 2.0f * (P[i] - 1.0f);
    float c = (float)(hist[labels[i]] - 1);
    float num = c * (2.0f + __logf(z)) - p;
    float den = c;

    snum[t] = num; sden[t] = den;
    __syncthreads();
    for (int s = 128; s > 0; s >>= 1) {
        if (t < s) { snum[t] += snum[t + s]; sden[t] += sden[t + s]; }
        __syncthreads();
    }
    if (t == 0) { atomicAdd(&nd[0], snum[0]); atomicAdd(&nd[1], sden[0]); }
}

// ---------------- kernel 4: scalar divide ----------------
__global__ void div_kernel(const float* __restrict__ nd, float* __restrict__ out) {
    out[0] = nd[0] / nd[1];
}

extern "C" void kernel_launch(void* const* d_in, const int* in_sizes, int n_in,
                              void* d_out, int out_size, void* d_ws, size_t ws_size,
                              hipStream_t stream) {
    const float* emb  = (const float*)d_in[0];
    const int* labels = (const int*)d_in[1];
    float* out = (float*)d_out;

    char* ws = (char*)d_ws;
    __hip_bfloat16* Ebf = (__hip_bfloat16*)ws;              // 4 MB
    float* Z  = (float*)(ws + (size_t)N * D * 2);           // 32 KB
    float* P  = Z + N;                                      // 32 KB
    float* nd = P + N;                                      // 8 B

    convert_kernel<<<(N * D / 4 + 255) / 256, 256, 0, stream>>>(
        (const float4*)emb, (ushort4*)Ebf, Z, P, nd);
    sim_kernel<<<ROWBLKS * COLBLKS, 256, 0, stream>>>(Ebf, labels, Z, P);
    finalize_kernel<<<N / 256, 256, 0, stream>>>(Z, P, labels, nd);
    div_kernel<<<1, 1, 0, stream>>>(nd, out);
}